// Round 3
// baseline (388.866 us; speedup 1.0000x reference)
//
#include <hip/hip_runtime.h>
#include <math.h>

// Problem: B=4, S=4096, H=2048, E=64, K=8; T = 16384 tokens.
#define HDIM 2048
#define TTOK 16384
#define NEXP 64
#define TOPK 8
#define SLEN 4096
#define NBATCH 4
#define KSPLIT 4
#define KRANGE 512            // HDIM / KSPLIT
#define PARTSZ (NEXP * TTOK)  // floats per k-split partial (4 MB)

// Output layout (flat, float32):
#define OFF_W    131072
#define OFF_LOSS 262144
#define OFF_LOAD 262145

// ws layout (float offsets): Pacc[4][64] @0, Cacc[4][64] @256, counter @512,
// part 4 x [64][16384] @1024.
#define WS_PACC 0
#define WS_CACC 256
#define WS_CNT  512
#define WS_PART 1024

// ---------------------------------------------------------------------------
// GEMM: grid 256 = 64 token-groups x 4 k-splits; block 512 = 8 waves.
// Wave (eh,eg): eh = k-half (256 k each), eg -> experts [16eg,16eg+16).
// Lane owns tokens 4l..4l+3 (granule l). x staged in LDS [32 k][256 tok]
// with 16B-granule XOR swizzle; per k-step: 1 ds_read_b128 -> 64 FMAs.
// W read row-major via wave-uniform s_load_dwordx4 (no transpose needed).
// End: k-halves reduced through LDS, partials stored [kh][e][tok].
__global__ __launch_bounds__(512, 2) void gate_gemm(
    const float* __restrict__ x,   // [16384][2048]
    const float* __restrict__ W,   // [64][2048]
    float* __restrict__ part) {    // 4 x [64][16384]
  __shared__ float xs[2][32 * 256];  // 64 KB double buffer

  const int tid = threadIdx.x;
  const int lane = tid & 63;
  const int wv = __builtin_amdgcn_readfirstlane(tid >> 6);  // 0..7
  const int eh = wv >> 2;   // k-half 0/1
  const int eg = wv & 3;    // expert group
  const int e0 = eg << 4;
  const int bid = blockIdx.x;
  const int kh = bid & 3;
  const int tg = bid >> 2;      // 0..63
  const int tok0 = tg << 8;     // 256 tokens/block
  const int kb = kh << 9;       // 512 k/block

  float4 acc[16];
#pragma unroll
  for (int j = 0; j < 16; ++j) acc[j] = make_float4(0.f, 0.f, 0.f, 0.f);

  // staging: thread -> token row tok_s (+64m), k-cols 4kq..4kq+3
  const int tok_s = tid >> 3;   // 0..63
  const int kq = tid & 7;       // 0..7
  const float* xp = x + (size_t)(tok0 + tok_s) * HDIM + kb + (kq << 2);

  float4 a[4];
#pragma unroll
  for (int m = 0; m < 4; ++m) a[m] = *(const float4*)(xp + (size_t)(m << 6) * HDIM);

  for (int kt = 0; kt < 16; ++kt) {
    float* xb = &xs[kt & 1][0];
    {
      const int gbase = tok_s >> 2;
      const int t3 = tok_s & 3;
#pragma unroll
      for (int m = 0; m < 4; ++m) {
        const float* av = (const float*)&a[m];
        const int g = gbase + (m << 4);
#pragma unroll
        for (int i = 0; i < 4; ++i) {
          const int r = (kq << 2) + i;           // LDS row (k within tile)
          const int gp = g ^ ((r >> 1) & 7);     // swizzle: stores <=2-way (free)
          xb[r * 256 + (gp << 2) + t3] = av[i];
        }
      }
    }
    __syncthreads();  // single barrier/tile; next store goes to other buffer
    if (kt < 15) {
      const float* np_ = xp + ((kt + 1) << 5);
#pragma unroll
      for (int m = 0; m < 4; ++m)
        a[m] = *(const float4*)(np_ + (size_t)(m << 6) * HDIM);
    }
    const float* wb = W + kb + (kt << 5) + (eh << 4);
#pragma unroll
    for (int kk0 = 0; kk0 < 16; kk0 += 4) {
      float4 xv[4];
#pragma unroll
      for (int q = 0; q < 4; ++q) {
        const int row = (eh << 4) + kk0 + q;
        xv[q] = *(const float4*)&xb[row * 256 + ((lane ^ ((row >> 1) & 7)) << 2)];
      }
#pragma unroll
      for (int j = 0; j < 16; ++j) {
        const float* wp = wb + (size_t)(e0 + j) * HDIM + kk0;  // uniform -> s_load
#pragma unroll
        for (int q = 0; q < 4; ++q) {
          const float w = wp[q];
          acc[j].x = fmaf(w, xv[q].x, acc[j].x);
          acc[j].y = fmaf(w, xv[q].y, acc[j].y);
          acc[j].z = fmaf(w, xv[q].z, acc[j].z);
          acc[j].w = fmaf(w, xv[q].w, acc[j].w);
        }
      }
    }
  }

  // reduce k-halves through LDS (reuse xs), then store partials
  __syncthreads();
  float* rbuf = &xs[0][0];  // 4 regions x 16 KB: [eg][j][lane*4..]
  if (eh == 1) {
    float* dst = rbuf + (eg << 12);
#pragma unroll
    for (int j = 0; j < 16; ++j)
      *(float4*)(dst + j * 256 + (lane << 2)) = acc[j];
  }
  __syncthreads();
  if (eh == 0) {
    const float* src = rbuf + (eg << 12);
#pragma unroll
    for (int j = 0; j < 16; ++j) {
      float4 o = *(const float4*)(src + j * 256 + (lane << 2));
      acc[j].x += o.x; acc[j].y += o.y; acc[j].z += o.z; acc[j].w += o.w;
      *(float4*)(part + (size_t)kh * PARTSZ + (size_t)(e0 + j) * TTOK + tok0 +
                 (lane << 2)) = acc[j];
    }
  }
}

// ---------------------------------------------------------------------------
// Epilogue: grid 128 x 128 threads; block covers 128 tokens x all 64 experts.
// Phase 1: cooperative coalesced sum of 4 partials into LDS le[e][tok].
// Phase 2: per-token sigmoid/top-8/weights. Phase 3: column P-stats + counts.
// Last block (atomic counter) computes loss + expert_load.
__global__ __launch_bounds__(128) void gate_epilogue(
    const float* __restrict__ part, const float* __restrict__ bias,
    float* __restrict__ out, float* __restrict__ Pacc,
    float* __restrict__ Cacc, int* __restrict__ counter) {
  __shared__ float le[64][132];   // logits [e][tok], pad 4
  __shared__ float rinv_sh[128];
  __shared__ unsigned csum[64];
  __shared__ int lastf;

  const int tid = threadIdx.x;
  const int t0 = blockIdx.x << 7;

  if (tid < 64) csum[tid] = 0u;

  // phase 1: 2048 float4 sums, 16 per thread, coalesced
#pragma unroll
  for (int w = 0; w < 16; ++w) {
    const int idx = (w << 7) + tid;
    const int e = idx >> 5;
    const int q = idx & 31;
    const float* p = part + (size_t)e * TTOK + t0 + (q << 2);
    float4 s0 = *(const float4*)(p);
    float4 s1 = *(const float4*)(p + PARTSZ);
    float4 s2 = *(const float4*)(p + 2 * PARTSZ);
    float4 s3 = *(const float4*)(p + 3 * PARTSZ);
    float4 s;
    s.x = (s0.x + s1.x) + (s2.x + s3.x);
    s.y = (s0.y + s1.y) + (s2.y + s3.y);
    s.z = (s0.z + s1.z) + (s2.z + s3.z);
    s.w = (s0.w + s1.w) + (s2.w + s3.w);
    *(float4*)&le[e][q << 2] = s;
  }
  __syncthreads();

  // phase 2: per-token
  float bl[64];
  float ssum = 0.f;
#pragma unroll
  for (int e = 0; e < NEXP; ++e) {
    float l = le[e][tid];
    ssum += 1.f / (1.f + expf(-l));
    bl[e] = l + bias[e];
  }
  rinv_sh[tid] = 1.f / (ssum + 1e-10f);

  unsigned long long chosen = 0ull;
  int i8[TOPK];
  float w8[TOPK];
  float wsum = 0.f;
#pragma unroll
  for (int j = 0; j < TOPK; ++j) {
    float best = -1e30f;
    int bi = 0;
    float braw = 0.f;
#pragma unroll
    for (int e = 0; e < NEXP; ++e) {
      bool ok = (((chosen >> e) & 1ull) == 0ull) && (bl[e] > best);
      if (ok) { best = bl[e]; bi = e; braw = bl[e] - bias[e]; }
    }
    chosen |= (1ull << bi);
    float sc = 1.f / (1.f + expf(-braw));
    i8[j] = bi;
    w8[j] = sc;
    wsum += sc;
  }
  const float inv = 1.f / (wsum + 1e-10f);
  const int t = t0 + tid;
  {
    float4 o;
    o.x = (float)i8[0]; o.y = (float)i8[1]; o.z = (float)i8[2]; o.w = (float)i8[3];
    *(float4*)(out + (size_t)t * TOPK) = o;
    o.x = (float)i8[4]; o.y = (float)i8[5]; o.z = (float)i8[6]; o.w = (float)i8[7];
    *(float4*)(out + (size_t)t * TOPK + 4) = o;
    o.x = w8[0] * inv; o.y = w8[1] * inv; o.z = w8[2] * inv; o.w = w8[3] * inv;
    *(float4*)(out + OFF_W + (size_t)t * TOPK) = o;
    o.x = w8[4] * inv; o.y = w8[5] * inv; o.z = w8[6] * inv; o.w = w8[7] * inv;
    *(float4*)(out + OFF_W + (size_t)t * TOPK + 4) = o;
  }
#pragma unroll
  for (int j = 0; j < TOPK; ++j) atomicAdd(&csum[i8[j]], 1u);
  __syncthreads();

  // phase 3: column sums (thread = expert) + global accumulation
  const int b = blockIdx.x >> 5;  // 32 blocks of 128 tokens per batch
  if (tid < 64) {
    float p = 0.f;
    for (int tt = 0; tt < 128; ++tt) {
      float sc = 1.f / (1.f + expf(-le[tid][tt]));
      p += sc * rinv_sh[tt];
    }
    atomicAdd(&Pacc[(b << 6) + tid], p);
    atomicAdd(&Cacc[(b << 6) + tid], (float)csum[tid]);
  }
  __syncthreads();
  __threadfence();
  if (tid == 0) {
    int old = __hip_atomic_fetch_add(counter, 1, __ATOMIC_ACQ_REL,
                                     __HIP_MEMORY_SCOPE_AGENT);
    lastf = (old == 127) ? 1 : 0;
  }
  __syncthreads();

  // last block: loss + expert_load
  if (lastf && tid < 64) {
    const int e = tid;
    float load = 0.f, partl = 0.f;
#pragma unroll
    for (int bb = 0; bb < NBATCH; ++bb) {
      float c = __hip_atomic_load(&Cacc[(bb << 6) + e], __ATOMIC_RELAXED,
                                  __HIP_MEMORY_SCOPE_AGENT);
      float p = __hip_atomic_load(&Pacc[(bb << 6) + e], __ATOMIC_RELAXED,
                                  __HIP_MEMORY_SCOPE_AGENT);
      load += c;
      partl += (c * (1.f / (TOPK * (float)SLEN))) * (p * (1.f / (float)SLEN));
    }
    out[OFF_LOAD + e] = load;
#pragma unroll
    for (int off = 32; off; off >>= 1) partl += __shfl_down(partl, off);
    if (e == 0) out[OFF_LOSS] = 0.01f * partl * (1.f / (float)NBATCH);
  }
}

// ---------------------------------------------------------------------------
extern "C" void kernel_launch(void* const* d_in, const int* in_sizes, int n_in,
                              void* d_out, int out_size, void* d_ws, size_t ws_size,
                              hipStream_t stream) {
  const float* x = (const float*)d_in[0];     // [4,4096,2048]
  const float* W = (const float*)d_in[1];     // [64,2048]
  const float* bias = (const float*)d_in[2];  // [64]
  float* out = (float*)d_out;

  float* ws = (float*)d_ws;
  float* Pacc = ws + WS_PACC;
  float* Cacc = ws + WS_CACC;
  int* counter = (int*)(ws + WS_CNT);
  float* part = ws + WS_PART;

  hipMemsetAsync(ws, 0, (WS_CNT + 4) * sizeof(float), stream);
  gate_gemm<<<256, 512, 0, stream>>>(x, W, part);
  gate_epilogue<<<128, 128, 0, stream>>>(part, bias, out, Pacc, Cacc, counter);
}

// Round 4
// 336.718 us; speedup vs baseline: 1.1549x; 1.1549x over previous
//
#include <hip/hip_runtime.h>
#include <math.h>

// Problem: B=4, S=4096, H=2048, E=64, K=8; T = 16384 tokens.
#define HDIM 2048
#define TTOK 16384
#define NEXP 64
#define TOPK 8
#define SLEN 4096
#define NBATCH 4
#define KSPLIT 4
#define KRANGE 512            // HDIM / KSPLIT
#define PARTSZ (NEXP * TTOK)  // floats per k-split partial (4 MB)

// Output layout (flat, float32):
#define OFF_W    131072
#define OFF_LOSS 262144
#define OFF_LOAD 262145

// ws layout (float offsets): Pacc[4][64] @0, Cacc[4][64] @256, counter @512,
// part 4 x [64][16384] @1024.
#define WS_PACC 0
#define WS_CACC 256
#define WS_CNT  512
#define WS_PART 1024

// ---------------------------------------------------------------------------
// GEMM: grid 1024 = 256 token-groups x 4 k-splits; block 256 = 4 waves.
// All waves share 64 tokens (lane = token); wave w owns experts [16w,16w+16).
// x tile [64 tok][32 k] in LDS, granule-XOR swizzle (conflict-free stores AND
// b128 reads). One ds_read_b128 feeds 64 FMAs. W read from original [e][k]
// layout via wave-uniform s_load (16 consecutive floats per row-chunk).
// Per-acc k order: strictly ascending within the 512-k split (= R2 FP order).
__global__ __launch_bounds__(256, 4) void gate_gemm(
    const float* __restrict__ x,   // [16384][2048]
    const float* __restrict__ W,   // [64][2048]
    float* __restrict__ part) {    // 4 x [64][16384]
  __shared__ float xs[2][64 * 32];  // 16 KB double buffer

  const int tid = threadIdx.x;
  const int lane = tid & 63;
  const int wv = __builtin_amdgcn_readfirstlane(tid >> 6);  // 0..3
  const int e0 = wv << 4;
  const int bid = blockIdx.x;
  const int kh = bid & 3;
  const int tg = bid >> 2;      // 0..255
  const int tok0 = tg << 6;     // 64 tokens/block
  const int kb = kh << 9;       // 512-k split

  float acc[16];
#pragma unroll
  for (int j = 0; j < 16; ++j) acc[j] = 0.f;

  // staging: thread -> rows stok and stok+32, granule sg (4 floats)
  const int stok = tid >> 3;    // 0..31
  const int sg = tid & 7;       // 0..7
  const int sgx = (sg ^ (stok & 7)) << 2;  // swizzled word offset in row
  const float* xp0 = x + (size_t)(tok0 + stok) * HDIM + kb + (sg << 2);
  const float* xp1 = xp0 + (size_t)32 * HDIM;

  float4 a0 = *(const float4*)xp0;
  float4 a1 = *(const float4*)xp1;

  const int rbase = lane << 5;        // lane's row (32 words)
  const int ls = lane & 7;            // read-side XOR

  for (int kt = 0; kt < 16; ++kt) {
    float* xb = &xs[kt & 1][0];
    *(float4*)&xb[(stok << 5) + sgx] = a0;
    *(float4*)&xb[((stok + 32) << 5) + sgx] = a1;
    __syncthreads();  // single barrier/tile (R2-proven dbuf pattern)
    if (kt < 15) {
      a0 = *(const float4*)(xp0 + ((kt + 1) << 5));
      a1 = *(const float4*)(xp1 + ((kt + 1) << 5));
    }
    // read own token's 32 k (8 x b128, conflict-free via XOR)
    float4 xv[8];
#pragma unroll
    for (int kk = 0; kk < 8; ++kk)
      xv[kk] = *(const float4*)&xb[rbase + ((kk ^ ls) << 2)];
    const float* xf = (const float*)&xv[0];  // xf[k], k = 0..31 logical

    const float* wb = W + (size_t)e0 * HDIM + kb + (kt << 5);
#pragma unroll
    for (int jg = 0; jg < 4; ++jg) {
      const float* w0 = wb + (size_t)(jg * 4 + 0) * HDIM;
      const float* w1 = wb + (size_t)(jg * 4 + 1) * HDIM;
      const float* w2 = wb + (size_t)(jg * 4 + 2) * HDIM;
      const float* w3 = wb + (size_t)(jg * 4 + 3) * HDIM;
#pragma unroll
      for (int h = 0; h < 2; ++h) {
#pragma unroll
        for (int k = 0; k < 16; ++k) {
          const int kk = (h << 4) + k;     // ascending k per acc chain
          const float xvv = xf[kk];
          acc[jg * 4 + 0] = fmaf(xvv, w0[kk], acc[jg * 4 + 0]);
          acc[jg * 4 + 1] = fmaf(xvv, w1[kk], acc[jg * 4 + 1]);
          acc[jg * 4 + 2] = fmaf(xvv, w2[kk], acc[jg * 4 + 2]);
          acc[jg * 4 + 3] = fmaf(xvv, w3[kk], acc[jg * 4 + 3]);
        }
      }
    }
  }

  // store partials: [kh][e][tok], coalesced dword per expert row
  float* dst = part + (size_t)kh * PARTSZ + (size_t)e0 * TTOK + tok0 + lane;
#pragma unroll
  for (int j = 0; j < 16; ++j) dst[(size_t)j * TTOK] = acc[j];
}

// ---------------------------------------------------------------------------
// Epilogue: grid 256 x 128 thr; block = 64 tokens x all 64 experts.
// Phase 1: coalesced pairwise sum of 4 partials -> LDS le[e][tok].
// Phase 2 (tid<64, thread=token): sigmoid/top-8/weights -> out.
// Phase 3 (tid<64, thread=expert): P-stat row sums + counts -> global atomics.
// Last block (atomic counter) computes loss + expert_load.
__global__ __launch_bounds__(128) void gate_epilogue(
    const float* __restrict__ part, const float* __restrict__ bias,
    float* __restrict__ out, float* __restrict__ Pacc,
    float* __restrict__ Cacc, int* __restrict__ counter) {
  __shared__ float le[64][65];   // [e][tok], stride 65
  __shared__ float rinv_sh[64];
  __shared__ unsigned csum[64];
  __shared__ int lastf;

  const int tid = threadIdx.x;
  const int t0 = blockIdx.x << 6;

  if (tid < 64) csum[tid] = 0u;

  // phase 1: 1024 float4 sums, 8 per thread, coalesced (256B runs)
#pragma unroll
  for (int w = 0; w < 8; ++w) {
    const int f = (w << 7) + tid;
    const int e = f >> 4;
    const int q = f & 15;
    const float* p = part + (size_t)e * TTOK + t0 + (q << 2);
    float4 s0 = *(const float4*)(p);
    float4 s1 = *(const float4*)(p + PARTSZ);
    float4 s2 = *(const float4*)(p + 2 * PARTSZ);
    float4 s3 = *(const float4*)(p + 3 * PARTSZ);
    le[e][(q << 2) + 0] = (s0.x + s1.x) + (s2.x + s3.x);
    le[e][(q << 2) + 1] = (s0.y + s1.y) + (s2.y + s3.y);
    le[e][(q << 2) + 2] = (s0.z + s1.z) + (s2.z + s3.z);
    le[e][(q << 2) + 3] = (s0.w + s1.w) + (s2.w + s3.w);
  }
  __syncthreads();

  // phase 2: per-token top-8
  if (tid < 64) {
    float bl[64];
    float ssum = 0.f;
#pragma unroll
    for (int e = 0; e < NEXP; ++e) {
      float l = le[e][tid];
      ssum += 1.f / (1.f + expf(-l));
      bl[e] = l + bias[e];
    }
    rinv_sh[tid] = 1.f / (ssum + 1e-10f);

    unsigned long long chosen = 0ull;
    int i8[TOPK];
    float w8[TOPK];
    float wsum = 0.f;
#pragma unroll
    for (int j = 0; j < TOPK; ++j) {
      float best = -1e30f;
      int bi = 0;
      float braw = 0.f;
#pragma unroll
      for (int e = 0; e < NEXP; ++e) {
        bool ok = (((chosen >> e) & 1ull) == 0ull) && (bl[e] > best);
        if (ok) { best = bl[e]; bi = e; braw = bl[e] - bias[e]; }
      }
      chosen |= (1ull << bi);
      float sc = 1.f / (1.f + expf(-braw));
      i8[j] = bi;
      w8[j] = sc;
      wsum += sc;
    }
    const float inv = 1.f / (wsum + 1e-10f);
    const int t = t0 + tid;
    float4 o;
    o.x = (float)i8[0]; o.y = (float)i8[1]; o.z = (float)i8[2]; o.w = (float)i8[3];
    *(float4*)(out + (size_t)t * TOPK) = o;
    o.x = (float)i8[4]; o.y = (float)i8[5]; o.z = (float)i8[6]; o.w = (float)i8[7];
    *(float4*)(out + (size_t)t * TOPK + 4) = o;
    o.x = w8[0] * inv; o.y = w8[1] * inv; o.z = w8[2] * inv; o.w = w8[3] * inv;
    *(float4*)(out + OFF_W + (size_t)t * TOPK) = o;
    o.x = w8[4] * inv; o.y = w8[5] * inv; o.z = w8[6] * inv; o.w = w8[7] * inv;
    *(float4*)(out + OFF_W + (size_t)t * TOPK + 4) = o;
#pragma unroll
    for (int j = 0; j < TOPK; ++j) atomicAdd(&csum[i8[j]], 1u);
  }
  __syncthreads();

  // phase 3: thread = expert; row sums of normalized scores
  const int b = blockIdx.x >> 6;  // 64 blocks of 64 tokens per batch
  if (tid < 64) {
    float p = 0.f;
    for (int tt = 0; tt < 64; ++tt) {
      float sc = 1.f / (1.f + expf(-le[tid][tt]));
      p += sc * rinv_sh[tt];
    }
    atomicAdd(&Pacc[(b << 6) + tid], p);
    atomicAdd(&Cacc[(b << 6) + tid], (float)csum[tid]);
  }
  __syncthreads();
  __threadfence();
  if (tid == 0) {
    int old = __hip_atomic_fetch_add(counter, 1, __ATOMIC_ACQ_REL,
                                     __HIP_MEMORY_SCOPE_AGENT);
    lastf = (old == 255) ? 1 : 0;
  }
  __syncthreads();

  if (lastf && tid < 64) {
    const int e = tid;
    float load = 0.f, partl = 0.f;
#pragma unroll
    for (int bb = 0; bb < NBATCH; ++bb) {
      float c = __hip_atomic_load(&Cacc[(bb << 6) + e], __ATOMIC_RELAXED,
                                  __HIP_MEMORY_SCOPE_AGENT);
      float p = __hip_atomic_load(&Pacc[(bb << 6) + e], __ATOMIC_RELAXED,
                                  __HIP_MEMORY_SCOPE_AGENT);
      load += c;
      partl += (c * (1.f / (TOPK * (float)SLEN))) * (p * (1.f / (float)SLEN));
    }
    out[OFF_LOAD + e] = load;
#pragma unroll
    for (int off = 32; off; off >>= 1) partl += __shfl_down(partl, off);
    if (e == 0) out[OFF_LOSS] = 0.01f * partl * (1.f / (float)NBATCH);
  }
}

// ---------------------------------------------------------------------------
extern "C" void kernel_launch(void* const* d_in, const int* in_sizes, int n_in,
                              void* d_out, int out_size, void* d_ws, size_t ws_size,
                              hipStream_t stream) {
  const float* x = (const float*)d_in[0];     // [4,4096,2048]
  const float* W = (const float*)d_in[1];     // [64,2048]
  const float* bias = (const float*)d_in[2];  // [64]
  float* out = (float*)d_out;

  float* ws = (float*)d_ws;
  float* Pacc = ws + WS_PACC;
  float* Cacc = ws + WS_CACC;
  int* counter = (int*)(ws + WS_CNT);
  float* part = ws + WS_PART;

  hipMemsetAsync(ws, 0, WS_PART * sizeof(float), stream);
  gate_gemm<<<1024, 256, 0, stream>>>(x, W, part);
  gate_epilogue<<<256, 128, 0, stream>>>(part, bias, out, Pacc, Cacc, counter);
}

// Round 5
// 268.928 us; speedup vs baseline: 1.4460x; 1.2521x over previous
//
#include <hip/hip_runtime.h>
#include <math.h>

// Problem: B=4, S=4096, H=2048, E=64, K=8; T = 16384 tokens.
#define HDIM 2048
#define TTOK 16384
#define NEXP 64
#define TOPK 8
#define SLEN 4096
#define NBATCH 4
#define PARTSZ (NEXP * TTOK)  // floats per k-split partial (4 MB)

// Output layout (flat, float32):
#define OFF_W    131072
#define OFF_LOSS 262144
#define OFF_LOAD 262145

// ws layout (float offsets): Pacc[4][64] @0, Cacc[4][64] @256, counter @512,
// Wt [2048][64] @1024, partials @WS_PART (KS x [64][16384]).
#define WS_PACC 0
#define WS_CACC 256
#define WS_CNT  512
#define WS_WT   1024
#define WS_PART (1024 + HDIM * NEXP)

// ---------------------------------------------------------------------------
// LDS-tiled transpose W [64][2048] -> Wt [2048][64] (R2-proven).
__global__ __launch_bounds__(256) void transpose_w(const float* __restrict__ W,
                                                   float* __restrict__ Wt) {
  __shared__ float tile[64][65];
  const int tid = threadIdx.x;
  const int k0 = blockIdx.x * 64;
  {
    const int kc = (tid & 15) << 2;
    const int er = tid >> 4;
#pragma unroll
    for (int i = 0; i < 4; ++i) {
      int e = er + i * 16;
      float4 v = *(const float4*)(W + (size_t)e * HDIM + k0 + kc);
      tile[e][kc + 0] = v.x; tile[e][kc + 1] = v.y;
      tile[e][kc + 2] = v.z; tile[e][kc + 3] = v.w;
    }
  }
  __syncthreads();
  {
    const int e4 = (tid & 15) << 2;
    const int kr = tid >> 4;
#pragma unroll
    for (int i = 0; i < 4; ++i) {
      int k = kr + i * 16;
      float4 v;
      v.x = tile[e4 + 0][k]; v.y = tile[e4 + 1][k];
      v.z = tile[e4 + 2][k]; v.w = tile[e4 + 3][k];
      *(float4*)(Wt + (size_t)(k0 + k) * NEXP + e4) = v;
    }
  }
}

// ---------------------------------------------------------------------------
// GEMM: grid KS*128; block 512 = 8 waves = 2 token-halves x 4 expert-groups.
// Block covers 128 tokens x 64 experts x (2048/KS) k. Lane = token.
// x tile [128 tok][32 k] in LDS, slot = granule ^ (row&7): every consecutive
// 8 lanes cover all 32 banks on store AND b128 read (R2-verified 0-conflict
// property). One ds_read_b128 feeds 64 FMAs; one s_load_dwordx16 feeds 16.
// Per-acc k strictly ascending within split (FP order = R2 family).
template <int KS>
__global__ __launch_bounds__(512, 8) void gate_gemm(
    const float* __restrict__ x,    // [16384][2048]
    const float* __restrict__ Wt,   // [2048][64]
    float* __restrict__ part) {     // KS x [64][16384]
  constexpr int KR = HDIM / KS;
  constexpr int NT = KR / 32;
  __shared__ float xs[2][128 * 32];  // 32 KB double buffer

  const int tid = threadIdx.x;
  const int lane = tid & 63;
  const int wv = __builtin_amdgcn_readfirstlane(tid >> 6);  // 0..7
  const int eg = wv & 3;        // expert group: [16eg, 16eg+16)
  const int th = wv >> 2;       // token half
  const int bid = blockIdx.x;
  const int kh = bid & (KS - 1);
  const int tg = bid >> (KS == 8 ? 3 : 2);
  const int tok0 = tg << 7;     // 128 tokens/block
  const int kb = kh * KR;

  float acc[16];
#pragma unroll
  for (int j = 0; j < 16; ++j) acc[j] = 0.f;

  // staging: thread -> rows r0 and r0+64, granule sg (16B), swizzled slot
  const int r0 = tid >> 3;      // 0..63
  const int sg = tid & 7;       // 0..7
  const int sslot = (sg ^ (r0 & 7)) << 2;
  const float* xp0 = x + (size_t)(tok0 + r0) * HDIM + kb + (sg << 2);
  const float* xp1 = xp0 + (size_t)64 * HDIM;
  float4 a0 = *(const float4*)xp0;
  float4 a1 = *(const float4*)xp1;

  const int myrow = (th << 6) + lane;
  const int rbase = myrow << 5;
  const int rs = lane & 7;      // == myrow & 7

  for (int kt = 0; kt < NT; ++kt) {
    float* xb = &xs[kt & 1][0];
    *(float4*)&xb[(r0 << 5) + sslot] = a0;
    *(float4*)&xb[((r0 + 64) << 5) + sslot] = a1;
    __syncthreads();  // single barrier/tile (R2-proven dbuf)
    if (kt + 1 < NT) {
      a0 = *(const float4*)(xp0 + ((kt + 1) << 5));
      a1 = *(const float4*)(xp1 + ((kt + 1) << 5));
    }
    const float* wkb = Wt + ((size_t)(kb + (kt << 5)) << 6) + (eg << 4);
#pragma unroll
    for (int c = 0; c < 8; ++c) {
      // slot (c^rs) of own row holds logical granule c -> k ascending
      float4 xv = *(const float4*)&xb[rbase + ((c ^ rs) << 2)];
      const float xf[4] = {xv.x, xv.y, xv.z, xv.w};
#pragma unroll
      for (int q = 0; q < 4; ++q) {
        const float* wr = wkb + (((c << 2) + q) << 6);  // uniform -> s_load_x16
#pragma unroll
        for (int j = 0; j < 16; ++j) acc[j] = fmaf(xf[q], wr[j], acc[j]);
      }
    }
  }

  // partial store [kh][e][tok], 64-lane coalesced per expert row
  float* dst = part + (size_t)kh * PARTSZ + ((size_t)(eg << 4)) * TTOK + tok0 +
               (th << 6) + lane;
#pragma unroll
  for (int j = 0; j < 16; ++j) dst[(size_t)j * TTOK] = acc[j];
}

// ---------------------------------------------------------------------------
// Epilogue (R4-proven shape): grid 256 x 128 thr; block = 64 tok x 64 e.
template <int KS>
__global__ __launch_bounds__(128) void gate_epilogue(
    const float* __restrict__ part, const float* __restrict__ bias,
    float* __restrict__ out, float* __restrict__ Pacc,
    float* __restrict__ Cacc, int* __restrict__ counter) {
  __shared__ float le[64][65];
  __shared__ float rinv_sh[64];
  __shared__ unsigned csum[64];
  __shared__ int lastf;

  const int tid = threadIdx.x;
  const int t0 = blockIdx.x << 6;

  if (tid < 64) csum[tid] = 0u;

  // phase 1: pairwise-tree sum of KS partials, coalesced
#pragma unroll
  for (int w = 0; w < 8; ++w) {
    const int f = (w << 7) + tid;
    const int e = f >> 4;
    const int q = f & 15;
    const float* p = part + (size_t)e * TTOK + t0 + (q << 2);
    float4 v[KS];
#pragma unroll
    for (int s = 0; s < KS; ++s) v[s] = *(const float4*)(p + (size_t)s * PARTSZ);
    float4 r;
    if (KS == 8) {
      r.x = ((v[0].x + v[1].x) + (v[2].x + v[3].x)) + ((v[4].x + v[5].x) + (v[6].x + v[7].x));
      r.y = ((v[0].y + v[1].y) + (v[2].y + v[3].y)) + ((v[4].y + v[5].y) + (v[6].y + v[7].y));
      r.z = ((v[0].z + v[1].z) + (v[2].z + v[3].z)) + ((v[4].z + v[5].z) + (v[6].z + v[7].z));
      r.w = ((v[0].w + v[1].w) + (v[2].w + v[3].w)) + ((v[4].w + v[5].w) + (v[6].w + v[7].w));
    } else {
      r.x = (v[0].x + v[1].x) + (v[2].x + v[3].x);
      r.y = (v[0].y + v[1].y) + (v[2].y + v[3].y);
      r.z = (v[0].z + v[1].z) + (v[2].z + v[3].z);
      r.w = (v[0].w + v[1].w) + (v[2].w + v[3].w);
    }
    le[e][(q << 2) + 0] = r.x; le[e][(q << 2) + 1] = r.y;
    le[e][(q << 2) + 2] = r.z; le[e][(q << 2) + 3] = r.w;
  }
  __syncthreads();

  // phase 2: per-token top-8 (thread = token)
  if (tid < 64) {
    float bl[64];
    float ssum = 0.f;
#pragma unroll
    for (int e = 0; e < NEXP; ++e) {
      float l = le[e][tid];
      ssum += 1.f / (1.f + expf(-l));
      bl[e] = l + bias[e];
    }
    rinv_sh[tid] = 1.f / (ssum + 1e-10f);

    unsigned long long chosen = 0ull;
    int i8[TOPK];
    float w8[TOPK];
    float wsum = 0.f;
#pragma unroll
    for (int j = 0; j < TOPK; ++j) {
      float best = -1e30f;
      int bi = 0;
      float braw = 0.f;
#pragma unroll
      for (int e = 0; e < NEXP; ++e) {
        bool ok = (((chosen >> e) & 1ull) == 0ull) && (bl[e] > best);
        if (ok) { best = bl[e]; bi = e; braw = bl[e] - bias[e]; }
      }
      chosen |= (1ull << bi);
      float sc = 1.f / (1.f + expf(-braw));
      i8[j] = bi;
      w8[j] = sc;
      wsum += sc;
    }
    const float inv = 1.f / (wsum + 1e-10f);
    const int t = t0 + tid;
    float4 o;
    o.x = (float)i8[0]; o.y = (float)i8[1]; o.z = (float)i8[2]; o.w = (float)i8[3];
    *(float4*)(out + (size_t)t * TOPK) = o;
    o.x = (float)i8[4]; o.y = (float)i8[5]; o.z = (float)i8[6]; o.w = (float)i8[7];
    *(float4*)(out + (size_t)t * TOPK + 4) = o;
    o.x = w8[0] * inv; o.y = w8[1] * inv; o.z = w8[2] * inv; o.w = w8[3] * inv;
    *(float4*)(out + OFF_W + (size_t)t * TOPK) = o;
    o.x = w8[4] * inv; o.y = w8[5] * inv; o.z = w8[6] * inv; o.w = w8[7] * inv;
    *(float4*)(out + OFF_W + (size_t)t * TOPK + 4) = o;
#pragma unroll
    for (int j = 0; j < TOPK; ++j) atomicAdd(&csum[i8[j]], 1u);
  }
  __syncthreads();

  // phase 3: thread = expert; row sums of normalized scores
  const int b = blockIdx.x >> 6;
  if (tid < 64) {
    float p = 0.f;
    for (int tt = 0; tt < 64; ++tt) {
      float sc = 1.f / (1.f + expf(-le[tid][tt]));
      p += sc * rinv_sh[tt];
    }
    atomicAdd(&Pacc[(b << 6) + tid], p);
    atomicAdd(&Cacc[(b << 6) + tid], (float)csum[tid]);
  }
  __syncthreads();
  __threadfence();
  if (tid == 0) {
    int old = __hip_atomic_fetch_add(counter, 1, __ATOMIC_ACQ_REL,
                                     __HIP_MEMORY_SCOPE_AGENT);
    lastf = (old == 255) ? 1 : 0;
  }
  __syncthreads();

  if (lastf && tid < 64) {
    const int e = tid;
    float load = 0.f, partl = 0.f;
#pragma unroll
    for (int bb = 0; bb < NBATCH; ++bb) {
      float c = __hip_atomic_load(&Cacc[(bb << 6) + e], __ATOMIC_RELAXED,
                                  __HIP_MEMORY_SCOPE_AGENT);
      float p = __hip_atomic_load(&Pacc[(bb << 6) + e], __ATOMIC_RELAXED,
                                  __HIP_MEMORY_SCOPE_AGENT);
      load += c;
      partl += (c * (1.f / (TOPK * (float)SLEN))) * (p * (1.f / (float)SLEN));
    }
    out[OFF_LOAD + e] = load;
#pragma unroll
    for (int off = 32; off; off >>= 1) partl += __shfl_down(partl, off);
    if (e == 0) out[OFF_LOSS] = 0.01f * partl * (1.f / (float)NBATCH);
  }
}

// ---------------------------------------------------------------------------
extern "C" void kernel_launch(void* const* d_in, const int* in_sizes, int n_in,
                              void* d_out, int out_size, void* d_ws, size_t ws_size,
                              hipStream_t stream) {
  const float* x = (const float*)d_in[0];     // [4,4096,2048]
  const float* W = (const float*)d_in[1];     // [64,2048]
  const float* bias = (const float*)d_in[2];  // [64]
  float* out = (float*)d_out;

  float* ws = (float*)d_ws;
  float* Pacc = ws + WS_PACC;
  float* Cacc = ws + WS_CACC;
  int* counter = (int*)(ws + WS_CNT);
  float* Wt = ws + WS_WT;
  float* part = ws + WS_PART;

  hipMemsetAsync(ws, 0, WS_WT * sizeof(float), stream);
  transpose_w<<<32, 256, 0, stream>>>(W, Wt);

  const size_t need8 = ((size_t)WS_PART + 8 * (size_t)PARTSZ) * sizeof(float);
  if (ws_size >= need8) {
    gate_gemm<8><<<1024, 512, 0, stream>>>(x, Wt, part);
    gate_epilogue<8><<<256, 128, 0, stream>>>(part, bias, out, Pacc, Cacc, counter);
  } else {
    gate_gemm<4><<<512, 512, 0, stream>>>(x, Wt, part);
    gate_epilogue<4><<<256, 128, 0, stream>>>(part, bias, out, Pacc, Cacc, counter);
  }
}